// Round 3
// baseline (766.171 us; speedup 1.0000x reference)
//
#include <hip/hip_runtime.h>
#include <hip/hip_bf16.h>

// MetaQDA MAP. D=640, C=64, N=1024, Q=2048, REG=0.3.
// sigma_c*denom = L L^T + U_c J_c U_c^T (rank 18) => Woodbury.
// Round 3: explicit blocked Linv (anti-diagonal steps, tiny) + one Yt GEMM;
// 128x64/8x4 f32 GEMM; split-K ip0; rowmap indirection (no Vmat).

#define D 640
#define C 64
#define NSUP 1024
#define Q 2048
#define KMAX 16
#define R18 18           // Woodbury rank: 1 (m) + 16 (x) + 1 (mu)
#define VROWS (C * R18)  // 1152
#define YROWS 3137       // 2048 Xq + 1024 X + 1 m + 64 mu

// ---------------- setup: class lists, scalars, rowmap --------------------
__global__ void k_setup(const int* __restrict__ y, const float* __restrict__ kappa,
                        const float* __restrict__ nu, const float* __restrict__ diag,
                        int* __restrict__ cnt, int* __restrict__ idx,
                        float* __restrict__ sc, float* __restrict__ rd,
                        int* __restrict__ rowmap) {
    __shared__ int lc[C];
    int tid = threadIdx.x;
    if (tid < C) lc[tid] = 0;
    __syncthreads();
    for (int n = tid; n < NSUP; n += 256) {
        int c = y[n];
        int k = atomicAdd(&lc[c], 1);
        if (k < KMAX) idx[c * KMAX + k] = n;
    }
    __syncthreads();
    for (int d = tid; d < D; d += 256) rd[d] = 1.0f / fabsf(diag[d]);
    if (tid < C) {
        int n = lc[tid]; if (n > KMAX) n = KMAX;
        cnt[tid] = n;
        float kap = fabsf(kappa[0]) + 1e-6f;
        float nuv = fmaxf(nu[0], (float)(D - 1) + 1e-6f);
        float Ncf = (float)n;
        sc[64 + tid]  = Ncf / (kap + Ncf);            // w_c
        sc[128 + tid] = nuv + Ncf + (float)(D + 2);   // denom_c
        sc[192 + tid] = -1.0f / (kap + Ncf);          // J^{-1} last diag
        if (tid == 0) { sc[0] = kap; sc[1] = nuv; }
    }
    __syncthreads();
    // rowmap[c*18+j] -> row of Yt holding that tilde-vector (-1 => zero row)
    for (int i = tid; i < VROWS; i += 256) {
        int c = i / R18, j = i - c * R18;
        int nc = lc[c] < KMAX ? lc[c] : KMAX;
        int rm;
        if (j == 0) rm = Q + NSUP;                       // m~
        else if (j <= KMAX) rm = (j - 1 < nc) ? Q + idx[c * KMAX + j - 1] : -1;
        else rm = Q + NSUP + 1 + c;                      // mu~
        rowmap[i] = rm;
    }
}

// ---------------- mu[c][d] = (1-w)*m + w*mean_c --------------------------
__global__ void k_mu(const float* __restrict__ X, const float* __restrict__ m,
                     const int* __restrict__ cnt, const int* __restrict__ idx,
                     const float* __restrict__ sc, float* __restrict__ mu) {
    int c = blockIdx.x;
    int d = blockIdx.y * 128 + threadIdx.x;
    int n = cnt[c];
    float s = 0.f;
    for (int k = 0; k < n; ++k) s += X[(size_t)idx[c * KMAX + k] * D + d];
    float w = sc[64 + c];
    float mean = (n > 0) ? s / (float)n : 0.f;
    mu[(size_t)c * D + d] = (1.f - w) * m[d] + w * mean;
}

// ---------------- Dinv: invert 5 diagonal 128x128 blocks into Linv -------
__global__ void k_dinv(const float* __restrict__ tlow, const float* __restrict__ rd,
                       float* __restrict__ Linv) {
    __shared__ float Lst[128 * 128];   // Lst[c][r] = rd_r * L[r][c], swizzled
    int tid = threadIdx.x;
    int b = blockIdx.x >> 5;                       // 5 blocks x 32 WGs
    int j = ((blockIdx.x & 31) << 2) + (tid >> 6); // column this wave solves
    int lane = tid & 63;
    int bB = b * 128;
    for (int e = tid; e < 128 * 128; e += 256) {
        int c = e & 127, r = e >> 7;
        float v;
        if (r == c) v = 1.0f;
        else if (r > c) v = rd[bB + r] * tlow[(size_t)(bB + r) * D + bB + c];
        else v = 0.f;
        Lst[c * 128 + (r ^ (c & 63))] = v;
    }
    __syncthreads();
    float rd0 = rd[bB + lane], rd1 = rd[bB + 64 + lane];
    float acc0 = 0.f, acc1 = 0.f, zz0 = 0.f, zz1 = 0.f;
    for (int i = j; i < 128; ++i) {
        int ri = i >> 6, il = i & 63;
        float av = (ri == 0) ? acc0 : acc1;
        float ai = __shfl(av, il);
        float zi = (i == j) ? __shfl((ri == 0) ? rd0 : rd1, il) : -ai;
        int sw = i & 63;
        float l0 = Lst[i * 128 + (lane ^ sw)];
        float l1 = Lst[i * 128 + 64 + (lane ^ sw)];
        if (lane > i) acc0 += l0 * zi;
        if (64 + lane > i) acc1 += l1 * zi;
        if (lane == i) zz0 = zi;
        if (64 + lane == i) zz1 = zi;
    }
    Linv[(size_t)(bB + lane) * D + bB + j] = zz0;
    Linv[(size_t)(bB + 64 + lane) * D + bB + j] = zz1;
}

// ---------------- Lhat_ik = Dinv_i * L_ik (strict-lower blocks) ----------
__global__ void k_lhat(const float* __restrict__ tlow, const float* __restrict__ Linv,
                       float* __restrict__ Lhat) {
    const int bi_tab[10] = {1, 2, 2, 3, 3, 3, 4, 4, 4, 4};
    const int bk_tab[10] = {0, 0, 1, 0, 1, 2, 0, 1, 2, 3};
    int p = blockIdx.y;
    int bi = bi_tab[p], bk = bk_tab[p];
    int tid = threadIdx.x;
    int c = tid & 127;
    int r = (blockIdx.x << 1) + (tid >> 7);
    const float* drow = Linv + (size_t)(bi * 128 + r) * D + bi * 128;  // Dinv_i row
    const float* lcol = tlow + (size_t)(bi * 128) * D + bk * 128 + c;
    float s = 0.f;
#pragma unroll 4
    for (int t = 0; t < 128; ++t) s += drow[t] * lcol[(size_t)t * D];
    Lhat[(size_t)(bi * 128 + r) * D + bk * 128 + c] = s;
}

// ---------------- Linv off-diag: anti-diagonal step g --------------------
// tile (i=k+g, k): Linv_ik = -sum_{j=k}^{i-1} Lhat_ij * Linv_jk
__global__ void k_linv_step(const float* __restrict__ Lhat, float* __restrict__ Linv,
                            int g) {
    __shared__ __align__(16) float As[16][132];  // Lhat 128 x 16
    __shared__ __align__(16) float Bs[16][36];   // Linv 16 x 32
    int tid = threadIdx.x;
    int tx = tid & 7, ty = tid >> 3;             // 8*4=32 cols, 32*4=128 rows
    int k = blockIdx.x, i = k + g;
    int rB = i * 128, kB = k * 128;
    int cB = kB + blockIdx.y * 32;
    int K = g * 128;
    float acc[4][4] = {};
    for (int kk = 0; kk < K; kk += 16) {
        __syncthreads();
        for (int t = tid; t < 128 * 16; t += 256) {
            int mm = t >> 4, kq = t & 15;
            As[kq][mm] = Lhat[(size_t)(rB + mm) * D + kB + kk + kq];
        }
        for (int t = tid; t < 32 * 16; t += 256) {
            int rr = t >> 5, cc = t & 31;
            Bs[rr][cc] = Linv[(size_t)(kB + kk + rr) * D + cB + cc];
        }
        __syncthreads();
#pragma unroll
        for (int kq = 0; kq < 16; ++kq) {
            float4 av = *(const float4*)&As[kq][ty * 4];
            float4 bv = *(const float4*)&Bs[kq][tx * 4];
            float aa[4] = {av.x, av.y, av.z, av.w};
            float bb[4] = {bv.x, bv.y, bv.z, bv.w};
#pragma unroll
            for (int i2 = 0; i2 < 4; ++i2)
#pragma unroll
                for (int j2 = 0; j2 < 4; ++j2) acc[i2][j2] += aa[i2] * bb[j2];
        }
    }
#pragma unroll
    for (int i2 = 0; i2 < 4; ++i2)
#pragma unroll
        for (int j2 = 0; j2 < 4; ++j2)
            Linv[(size_t)(rB + ty * 4 + i2) * D + cB + tx * 4 + j2] = -acc[i2][j2];
}

// ---------------- gather Ycat = [Xq; X; m; mu] ---------------------------
__global__ void k_gather_y(const float* __restrict__ Xq, const float* __restrict__ X,
                           const float* __restrict__ m, const float* __restrict__ mu,
                           float* __restrict__ Ycat) {
    int r = blockIdx.x;
    const float* src;
    if (r < Q) src = Xq + (size_t)r * D;
    else if (r < Q + NSUP) src = X + (size_t)(r - Q) * D;
    else if (r == Q + NSUP) src = m;
    else src = mu + (size_t)(r - (Q + NSUP + 1)) * D;
    for (int d = threadIdx.x; d < D; d += 256) Ycat[(size_t)r * D + d] = src[d];
}

// ---------------- f32 NT GEMM, 128x64 tile, 8x4 micro --------------------
// Out[r][n] = sum_k A[r][k] * B[brow(n)][k]; brow via optional rowmap.
// grid.z = split-K chunk (k0 = z*ksteps*16, Out += z*kzstride).
__global__ void k_gemm2(const float* __restrict__ A, const float* __restrict__ B,
                        const int* __restrict__ rowmap, float* __restrict__ Out,
                        int M, int Nn, int ksteps, int kzstride) {
    __shared__ __align__(16) float As[16][132];
    __shared__ __align__(16) float Bs[16][68];
    int tid = threadIdx.x;
    int tx = tid & 15, ty = tid >> 4;   // 16*4=64 cols, 16*8=128 rows
    int rowBase = blockIdx.y * 128, colBase = blockIdx.x * 64;
    int k0 = blockIdx.z * ksteps * 16;
    float* Oz = Out + (size_t)blockIdx.z * kzstride;
    float acc[8][4] = {};
    for (int s = 0; s < ksteps; ++s) {
        int kk = k0 + s * 16;
        __syncthreads();
        for (int i = tid; i < 128 * 16; i += 256) {
            int mm = i >> 4, k = i & 15;
            int gr = rowBase + mm;
            As[k][mm] = (gr < M) ? A[(size_t)gr * D + kk + k] : 0.f;
        }
        for (int i = tid; i < 64 * 16; i += 256) {
            int mm = i >> 4, k = i & 15;
            int gc = colBase + mm;
            int br = rowmap ? ((gc < Nn) ? rowmap[gc] : -1) : ((gc < Nn) ? gc : -1);
            Bs[k][mm] = (br >= 0) ? B[(size_t)br * D + kk + k] : 0.f;
        }
        __syncthreads();
#pragma unroll
        for (int k = 0; k < 16; ++k) {
            float4 a0 = *(const float4*)&As[k][ty * 8];
            float4 a1 = *(const float4*)&As[k][ty * 8 + 4];
            float4 bv = *(const float4*)&Bs[k][tx * 4];
            float aa[8] = {a0.x, a0.y, a0.z, a0.w, a1.x, a1.y, a1.z, a1.w};
            float bb[4] = {bv.x, bv.y, bv.z, bv.w};
#pragma unroll
            for (int i2 = 0; i2 < 8; ++i2)
#pragma unroll
                for (int j2 = 0; j2 < 4; ++j2) acc[i2][j2] += aa[i2] * bb[j2];
        }
    }
#pragma unroll
    for (int i2 = 0; i2 < 8; ++i2) {
        int gr = rowBase + ty * 8 + i2;
        if (gr >= M) continue;
#pragma unroll
        for (int j2 = 0; j2 < 4; ++j2) {
            int gc = colBase + tx * 4 + j2;
            if (gc < Nn) Oz[(size_t)gr * Nn + gc] = acc[i2][j2];
        }
    }
}

// ---------------- row norms of Yt (->at) and Ycat (->a0), Q rows ---------
__global__ void k_rownorm2(const float* __restrict__ Yt, const float* __restrict__ Ycat,
                           float* __restrict__ at, float* __restrict__ a0) {
    int gw = (blockIdx.x * 256 + threadIdx.x) >> 6;
    int lane = threadIdx.x & 63;
    const float* row = (blockIdx.y ? Ycat : Yt) + (size_t)gw * D;
    float s = 0.f;
    for (int d = lane; d < D; d += 64) { float v = row[d]; s += v * v; }
#pragma unroll
    for (int off = 32; off; off >>= 1) s += __shfl_xor(s, off);
    if (lane == 0) (blockIdx.y ? a0 : at)[gw] = s;
}

// ---------------- per-class: Gram, K = J^{-1}+Gram, Kinv, h, btil, b0 ----
__global__ void k_class(const float* __restrict__ Yt, const int* __restrict__ rowmap,
                        const float* __restrict__ mu, const float* __restrict__ sc,
                        float* __restrict__ h, float* __restrict__ btil,
                        float* __restrict__ b0, float* __restrict__ kinv) {
    __shared__ float sv[R18][D + 4];
    __shared__ float aug[R18][40];
    __shared__ float red[256];
    __shared__ int piv;
    __shared__ float pv;
    int c = blockIdx.x, tid = threadIdx.x;
    for (int i = tid; i < R18 * D; i += 256) {
        int r = i / D, d = i - r * D;
        int rm = rowmap[c * R18 + r];
        sv[r][d] = (rm >= 0) ? Yt[(size_t)rm * D + d] : 0.f;
    }
    __syncthreads();
    // Gram: wave-parallel dot products (lane-strided over D)
    int wv = tid >> 6, lane = tid & 63;
    for (int p = wv; p < 171; p += 4) {
        int i = 0, rem = p;
        while (rem >= R18 - i) { rem -= R18 - i; ++i; }
        int j = i + rem;
        float s = 0.f;
        for (int d = lane; d < D; d += 64) s += sv[i][d] * sv[j][d];
#pragma unroll
        for (int off = 32; off; off >>= 1) s += __shfl_xor(s, off);
        if (lane == 0) { aug[i][j] = s; aug[j][i] = s; }
    }
    __syncthreads();
    if (tid < R18) h[c * R18 + tid] = aug[tid][R18 - 1];
    if (tid == 0) btil[c] = aug[R18 - 1][R18 - 1];
    float s0 = 0.f;
    for (int d = tid; d < D; d += 256) { float v = mu[(size_t)c * D + d]; s0 += v * v; }
    red[tid] = s0;
    __syncthreads();
    for (int st = 128; st; st >>= 1) { if (tid < st) red[tid] += red[tid + st]; __syncthreads(); }
    if (tid == 0) {
        b0[c] = red[0];
        aug[0][0] += 1.0f / sc[0];
        for (int t = 1; t <= KMAX; ++t) aug[t][t] += 1.0f;
        aug[R18 - 1][R18 - 1] += sc[192 + c];
    }
    for (int i = tid; i < R18 * R18; i += 256)
        aug[i / R18][R18 + i % R18] = (i / R18 == i % R18) ? 1.f : 0.f;
    __syncthreads();
    for (int p = 0; p < R18; ++p) {
        if (tid == 0) {
            int bi = p; float bv = fabsf(aug[p][p]);
            for (int r = p + 1; r < R18; ++r) {
                float v = fabsf(aug[r][p]);
                if (v > bv) { bv = v; bi = r; }
            }
            piv = bi;
        }
        __syncthreads();
        if (piv != p && tid < 2 * R18) {
            float t = aug[p][tid]; aug[p][tid] = aug[piv][tid]; aug[piv][tid] = t;
        }
        __syncthreads();
        if (tid == 0) pv = aug[p][p];
        __syncthreads();
        if (tid < 2 * R18) aug[p][tid] /= pv;
        __syncthreads();
        if (tid < R18) red[tid] = aug[tid][p];
        __syncthreads();
        for (int i = tid; i < R18 * 2 * R18; i += 256) {
            int r = i / (2 * R18), col = i % (2 * R18);
            if (r != p) aug[r][col] -= red[r] * aug[p][col];
        }
        __syncthreads();
    }
    for (int i = tid; i < R18 * R18; i += 256)
        kinv[(size_t)c * R18 * R18 + i] = aug[i / R18][R18 + i % R18];
}

// ---------------- epilogue ----------------------------------------------
__global__ void k_epi(const float* __restrict__ G, const float* __restrict__ ip0p,
                      const float* __restrict__ at, const float* __restrict__ a0,
                      const float* __restrict__ h, const float* __restrict__ btil,
                      const float* __restrict__ b0, const float* __restrict__ kinv,
                      const float* __restrict__ sc, float* __restrict__ out) {
    __shared__ float lk[R18 * R18], lh[R18];
    __shared__ float ldn, lbt, lb0;
    int c = blockIdx.x, tid = threadIdx.x;
    for (int i = tid; i < R18 * R18; i += 256) lk[i] = kinv[(size_t)c * R18 * R18 + i];
    if (tid < R18) lh[tid] = h[c * R18 + tid];
    if (tid == 0) { ldn = sc[128 + c]; lbt = btil[c]; lb0 = b0[c]; }
    __syncthreads();
    int q = blockIdx.y * 256 + tid;
    const float* Gr = G + (size_t)q * VROWS + c * R18;
    float g[R18];
#pragma unroll
    for (int j = 0; j < R18; ++j) g[j] = Gr[j];
    float ipt = g[R18 - 1];
#pragma unroll
    for (int j = 0; j < R18; ++j) g[j] -= lh[j];
    float corr = 0.f;
#pragma unroll
    for (int i = 0; i < R18; ++i) {
        float s = 0.f;
#pragma unroll
        for (int j = 0; j < R18; ++j) s += lk[i * R18 + j] * g[j];
        corr += g[i] * s;
    }
    float ip0 = 0.f;
#pragma unroll
    for (int z = 0; z < 5; ++z) ip0 += ip0p[(size_t)z * Q * C + (size_t)q * C + c];
    float tt = at[q] - 2.f * ipt + lbt;
    float t0 = a0[q] - 2.f * ip0 + lb0;
    out[(size_t)q * C + c] = -(0.7f * ldn * (tt - corr) + 0.3f * t0);
}

extern "C" void kernel_launch(void* const* d_in, const int* in_sizes, int n_in,
                              void* d_out, int out_size, void* d_ws, size_t ws_size,
                              hipStream_t stream) {
    const float* X     = (const float*)d_in[0];
    const int*   y     = (const int*)d_in[1];
    const float* Xq    = (const float*)d_in[2];
    const float* m     = (const float*)d_in[3];
    const float* kappa = (const float*)d_in[4];
    const float* nu    = (const float*)d_in[5];
    const float* tdiag = (const float*)d_in[6];
    const float* tlow  = (const float*)d_in[7];
    float* out = (float*)d_out;

    char* w = (char*)d_ws;
    auto alloc = [&](size_t bytes) {
        char* p = w;
        w += (bytes + 255) & ~(size_t)255;
        return p;
    };
    int*   cnt    = (int*)alloc(C * 4);
    int*   idx    = (int*)alloc(C * KMAX * 4);
    int*   rowmap = (int*)alloc(VROWS * 4);
    float* sc     = (float*)alloc(256 * 4);
    float* rd     = (float*)alloc(D * 4);
    float* mu     = (float*)alloc((size_t)C * D * 4);
    float* at     = (float*)alloc(Q * 4);
    float* a0     = (float*)alloc(Q * 4);
    float* h      = (float*)alloc(C * R18 * 4);
    float* btil   = (float*)alloc(C * 4);
    float* b0     = (float*)alloc(C * 4);
    float* kinv   = (float*)alloc((size_t)C * R18 * R18 * 4);
    float* Ycat   = (float*)alloc((size_t)YROWS * D * 4);
    float* Yt     = (float*)alloc((size_t)YROWS * D * 4);
    float* ip0p   = (float*)alloc((size_t)5 * Q * C * 4);
    // Linv+Lhat dead after the Yt GEMM; alias G over them (stream-ordered).
    char*  wmark  = w;
    float* Linv   = (float*)alloc((size_t)D * D * 4);
    float* Lhat   = (float*)alloc((size_t)D * D * 4);
    w = wmark;
    float* G      = (float*)alloc((size_t)Q * VROWS * 4 + 2 * (size_t)D * D * 4);

    hipMemsetAsync(Linv, 0, (size_t)D * D * 4, stream);
    k_setup<<<1, 256, 0, stream>>>(y, kappa, nu, tdiag, cnt, idx, sc, rd, rowmap);
    k_mu<<<dim3(C, D / 128), 128, 0, stream>>>(X, m, cnt, idx, sc, mu);
    k_dinv<<<160, 256, 0, stream>>>(tlow, rd, Linv);
    k_lhat<<<dim3(64, 10), 256, 0, stream>>>(tlow, Linv, Lhat);
    for (int g = 1; g <= 4; ++g)
        k_linv_step<<<dim3(5 - g, 4), 256, 0, stream>>>(Lhat, Linv, g);
    k_gather_y<<<YROWS, 256, 0, stream>>>(Xq, X, m, mu, Ycat);
    // Yt = Ycat * Linv^T
    k_gemm2<<<dim3(D / 64, (YROWS + 127) / 128), 256, 0, stream>>>(
        Ycat, Linv, nullptr, Yt, YROWS, D, D / 16, 0);
    k_rownorm2<<<dim3(Q / 4, 2), 256, 0, stream>>>(Yt, Ycat, at, a0);
    k_class<<<C, 256, 0, stream>>>(Yt, rowmap, mu, sc, h, btil, b0, kinv);
    // G[q][c*18+j] = x~q . v~_{c,j}  (B rows of Yt via rowmap)
    k_gemm2<<<dim3(VROWS / 64, Q / 128), 256, 0, stream>>>(
        Yt, Yt, rowmap, G, Q, VROWS, D / 16, 0);
    // ip0 partials: split-K over 5 chunks of 128
    k_gemm2<<<dim3(1, Q / 128, 5), 256, 0, stream>>>(
        Ycat, mu, nullptr, ip0p, Q, C, 8, Q * C);
    k_epi<<<dim3(C, Q / 256), 256, 0, stream>>>(G, ip0p, at, a0, h, btil, b0, kinv, sc, out);
}

// Round 4
// 491.787 us; speedup vs baseline: 1.5579x; 1.5579x over previous
//
#include <hip/hip_runtime.h>
#include <hip/hip_bf16.h>

// MetaQDA MAP. D=640, C=64, N=1024, Q=2048, REG=0.3.
// sigma_c*denom = L L^T + U_c J_c U_c^T (rank 18) => Woodbury.
// Round 4: split-bf16 (hi/lo) MFMA for both big GEMMs; ip0 folded into the
// Yt GEMM as 64 extra B-rows (mu); no Ycat buffer; 64x64 tiles (576 WGs).

#define D 640
#define C 64
#define NSUP 1024
#define Q 2048
#define KMAX 16
#define R18 18           // Woodbury rank: 1 (m) + 16 (x) + 1 (mu)
#define VROWS (C * R18)  // 1152
#define YROWS 3137       // 2048 Xq + 1024 X + 1 m + 64 mu
#define YPAD 3200
#define NEXT 704         // 640 tilde cols + 64 ip0 cols

typedef __attribute__((ext_vector_type(8))) short bf16x8;
typedef __attribute__((ext_vector_type(4))) float floatx4;

__device__ __forceinline__ unsigned short f2bf(float x) {
    unsigned int u = __float_as_uint(x);
    unsigned int r = u + 0x7FFFu + ((u >> 16) & 1u);
    return (unsigned short)(r >> 16);
}

// ---------------- setup: class lists, scalars, rowmap --------------------
__global__ void k_setup(const int* __restrict__ y, const float* __restrict__ kappa,
                        const float* __restrict__ nu, const float* __restrict__ diag,
                        int* __restrict__ cnt, int* __restrict__ idx,
                        float* __restrict__ sc, float* __restrict__ rd,
                        int* __restrict__ rowmap) {
    __shared__ int lc[C];
    int tid = threadIdx.x;
    if (tid < C) lc[tid] = 0;
    __syncthreads();
    for (int n = tid; n < NSUP; n += 256) {
        int c = y[n];
        int k = atomicAdd(&lc[c], 1);
        if (k < KMAX) idx[c * KMAX + k] = n;
    }
    __syncthreads();
    for (int d = tid; d < D; d += 256) rd[d] = 1.0f / fabsf(diag[d]);
    if (tid < C) {
        int n = lc[tid]; if (n > KMAX) n = KMAX;
        cnt[tid] = n;
        float kap = fabsf(kappa[0]) + 1e-6f;
        float nuv = fmaxf(nu[0], (float)(D - 1) + 1e-6f);
        float Ncf = (float)n;
        sc[64 + tid]  = Ncf / (kap + Ncf);            // w_c
        sc[128 + tid] = nuv + Ncf + (float)(D + 2);   // denom_c
        sc[192 + tid] = -1.0f / (kap + Ncf);          // J^{-1} last diag
        if (tid == 0) { sc[0] = kap; sc[1] = nuv; }
    }
    __syncthreads();
    for (int i = tid; i < VROWS; i += 256) {
        int c = i / R18, j = i - c * R18;
        int nc = lc[c] < KMAX ? lc[c] : KMAX;
        int rm;
        if (j == 0) rm = Q + NSUP;                       // m~
        else if (j <= KMAX) rm = (j - 1 < nc) ? Q + idx[c * KMAX + j - 1] : -1;
        else rm = Q + NSUP + 1 + c;                      // mu~
        rowmap[i] = rm;
    }
}

// ---------------- mu[c][d] = (1-w)*m + w*mean_c --------------------------
__global__ void k_mu(const float* __restrict__ X, const float* __restrict__ m,
                     const int* __restrict__ cnt, const int* __restrict__ idx,
                     const float* __restrict__ sc, float* __restrict__ mu) {
    int c = blockIdx.x;
    int d = blockIdx.y * 128 + threadIdx.x;
    int n = cnt[c];
    float s = 0.f;
    for (int k = 0; k < n; ++k) s += X[(size_t)idx[c * KMAX + k] * D + d];
    float w = sc[64 + c];
    float mean = (n > 0) ? s / (float)n : 0.f;
    mu[(size_t)c * D + d] = (1.f - w) * m[d] + w * mean;
}

// ---------------- Dinv: invert 5 diagonal 128x128 blocks into Linv -------
__global__ void k_dinv(const float* __restrict__ tlow, const float* __restrict__ rd,
                       float* __restrict__ Linv) {
    __shared__ float Lst[128 * 128];
    int tid = threadIdx.x;
    int b = blockIdx.x >> 5;
    int j = ((blockIdx.x & 31) << 2) + (tid >> 6);
    int lane = tid & 63;
    int bB = b * 128;
    for (int e = tid; e < 128 * 128; e += 256) {
        int c = e & 127, r = e >> 7;
        float v;
        if (r == c) v = 1.0f;
        else if (r > c) v = rd[bB + r] * tlow[(size_t)(bB + r) * D + bB + c];
        else v = 0.f;
        Lst[c * 128 + (r ^ (c & 63))] = v;
    }
    __syncthreads();
    float rd0 = rd[bB + lane], rd1 = rd[bB + 64 + lane];
    float acc0 = 0.f, acc1 = 0.f, zz0 = 0.f, zz1 = 0.f;
    for (int i = j; i < 128; ++i) {
        int ri = i >> 6, il = i & 63;
        float av = (ri == 0) ? acc0 : acc1;
        float ai = __shfl(av, il);
        float zi = (i == j) ? __shfl((ri == 0) ? rd0 : rd1, il) : -ai;
        int sw = i & 63;
        float l0 = Lst[i * 128 + (lane ^ sw)];
        float l1 = Lst[i * 128 + 64 + (lane ^ sw)];
        if (lane > i) acc0 += l0 * zi;
        if (64 + lane > i) acc1 += l1 * zi;
        if (lane == i) zz0 = zi;
        if (64 + lane == i) zz1 = zi;
    }
    Linv[(size_t)(bB + lane) * D + bB + j] = zz0;
    Linv[(size_t)(bB + 64 + lane) * D + bB + j] = zz1;
}

// ---------------- Lhat_ik = Dinv_i * L_ik (strict-lower blocks) ----------
__global__ void k_lhat(const float* __restrict__ tlow, const float* __restrict__ Linv,
                       float* __restrict__ Lhat) {
    const int bi_tab[10] = {1, 2, 2, 3, 3, 3, 4, 4, 4, 4};
    const int bk_tab[10] = {0, 0, 1, 0, 1, 2, 0, 1, 2, 3};
    int p = blockIdx.y;
    int bi = bi_tab[p], bk = bk_tab[p];
    int tid = threadIdx.x;
    int c = tid & 127;
    int r = (blockIdx.x << 1) + (tid >> 7);
    const float* drow = Linv + (size_t)(bi * 128 + r) * D + bi * 128;
    const float* lcol = tlow + (size_t)(bi * 128) * D + bk * 128 + c;
    float s = 0.f;
#pragma unroll 4
    for (int t = 0; t < 128; ++t) s += drow[t] * lcol[(size_t)t * D];
    Lhat[(size_t)(bi * 128 + r) * D + bk * 128 + c] = s;
}

// ---------------- Linv off-diag: anti-diagonal step g --------------------
__global__ void k_linv_step(const float* __restrict__ Lhat, float* __restrict__ Linv,
                            int g) {
    __shared__ __align__(16) float As[16][132];
    __shared__ __align__(16) float Bs[16][36];
    int tid = threadIdx.x;
    int tx = tid & 7, ty = tid >> 3;
    int k = blockIdx.x, i = k + g;
    int rB = i * 128, kB = k * 128;
    int cB = kB + blockIdx.y * 32;
    int K = g * 128;
    float acc[4][4] = {};
    for (int kk = 0; kk < K; kk += 16) {
        __syncthreads();
        for (int t = tid; t < 128 * 16; t += 256) {
            int mm = t >> 4, kq = t & 15;
            As[kq][mm] = Lhat[(size_t)(rB + mm) * D + kB + kk + kq];
        }
        for (int t = tid; t < 32 * 16; t += 256) {
            int rr = t >> 5, cc = t & 31;
            Bs[rr][cc] = Linv[(size_t)(kB + kk + rr) * D + cB + cc];
        }
        __syncthreads();
#pragma unroll
        for (int kq = 0; kq < 16; ++kq) {
            float4 av = *(const float4*)&As[kq][ty * 4];
            float4 bv = *(const float4*)&Bs[kq][tx * 4];
            float aa[4] = {av.x, av.y, av.z, av.w};
            float bb[4] = {bv.x, bv.y, bv.z, bv.w};
#pragma unroll
            for (int i2 = 0; i2 < 4; ++i2)
#pragma unroll
                for (int j2 = 0; j2 < 4; ++j2) acc[i2][j2] += aa[i2] * bb[j2];
        }
    }
#pragma unroll
    for (int i2 = 0; i2 < 4; ++i2)
#pragma unroll
        for (int j2 = 0; j2 < 4; ++j2)
            Linv[(size_t)(rB + ty * 4 + i2) * D + cB + tx * 4 + j2] = -acc[i2][j2];
}

// ---------------- pack A-side: [Xq; X; m; mu] -> hi/lo bf16 [3200x640] ---
__global__ void k_pack_src(const float* __restrict__ Xq, const float* __restrict__ X,
                           const float* __restrict__ m, const float* __restrict__ mu,
                           unsigned short* __restrict__ hi, unsigned short* __restrict__ lo) {
    int gid = blockIdx.x * 256 + threadIdx.x;       // one per 4 elems
    int row = gid / 160, c = (gid - row * 160) * 4;
    if (row >= YPAD) return;
    float4 v = {0.f, 0.f, 0.f, 0.f};
    if (row < Q) v = *(const float4*)(Xq + (size_t)row * D + c);
    else if (row < Q + NSUP) v = *(const float4*)(X + (size_t)(row - Q) * D + c);
    else if (row == Q + NSUP) v = *(const float4*)(m + c);
    else if (row < YROWS) v = *(const float4*)(mu + (size_t)(row - (Q + NSUP + 1)) * D + c);
    float vv[4] = {v.x, v.y, v.z, v.w};
    ushort4 h, l;
    unsigned short* hp = (unsigned short*)&h;
    unsigned short* lp = (unsigned short*)&l;
#pragma unroll
    for (int i = 0; i < 4; ++i) {
        unsigned short hb = f2bf(vv[i]);
        float hf = __uint_as_float((unsigned int)hb << 16);
        hp[i] = hb;
        lp[i] = f2bf(vv[i] - hf);
    }
    *(ushort4*)(hi + (size_t)row * D + c) = h;
    *(ushort4*)(lo + (size_t)row * D + c) = l;
}

// ---------------- pack B-side: [Linv (upper masked); mu] -> [704x640] ----
__global__ void k_pack_b(const float* __restrict__ Linv, const float* __restrict__ mu,
                         unsigned short* __restrict__ hi, unsigned short* __restrict__ lo) {
    int gid = blockIdx.x * 256 + threadIdx.x;
    int row = gid / 160, c = (gid - row * 160) * 4;
    if (row >= NEXT) return;
    float4 v;
    if (row < D) v = *(const float4*)(Linv + (size_t)row * D + c);
    else v = *(const float4*)(mu + (size_t)(row - D) * D + c);
    float vv[4] = {v.x, v.y, v.z, v.w};
    ushort4 h, l;
    unsigned short* hp = (unsigned short*)&h;
    unsigned short* lp = (unsigned short*)&l;
#pragma unroll
    for (int i = 0; i < 4; ++i) {
        float x = (row < D && c + i > row) ? 0.f : vv[i];   // strict upper = 0
        unsigned short hb = f2bf(x);
        float hf = __uint_as_float((unsigned int)hb << 16);
        hp[i] = hb;
        lp[i] = f2bf(x - hf);
    }
    *(ushort4*)(hi + (size_t)row * D + c) = h;
    *(ushort4*)(lo + (size_t)row * D + c) = l;
}

// ---------------- pack Yt (f32, ld=704, cols 0..639) -> hi/lo ------------
__global__ void k_pack_t(const float* __restrict__ Yt,
                         unsigned short* __restrict__ hi, unsigned short* __restrict__ lo) {
    int gid = blockIdx.x * 256 + threadIdx.x;
    int row = gid / 160, c = (gid - row * 160) * 4;
    if (row >= YPAD) return;
    float4 v = *(const float4*)(Yt + (size_t)row * NEXT + c);
    float vv[4] = {v.x, v.y, v.z, v.w};
    ushort4 h, l;
    unsigned short* hp = (unsigned short*)&h;
    unsigned short* lp = (unsigned short*)&l;
#pragma unroll
    for (int i = 0; i < 4; ++i) {
        unsigned short hb = f2bf(vv[i]);
        float hf = __uint_as_float((unsigned int)hb << 16);
        hp[i] = hb;
        lp[i] = f2bf(vv[i] - hf);
    }
    *(ushort4*)(hi + (size_t)row * D + c) = h;
    *(ushort4*)(lo + (size_t)row * D + c) = l;
}

// ---------------- split-bf16 MFMA NT GEMM, 64x64 tile --------------------
// Out[r][n] = sum_k A[r][k]*B[brow(n)][k], A = Ah+Al, B = Bh+Bl (bf16 pairs)
// 3-term: Ah*Bh + Ah*Bl + Al*Bh. K = 640. 4 waves; wave w -> rows 16w..16w+15.
__global__ __launch_bounds__(256) void k_mfma_nt(
        const unsigned short* __restrict__ Ah, const unsigned short* __restrict__ Al,
        const unsigned short* __restrict__ Bh, const unsigned short* __restrict__ Bl,
        const int* __restrict__ rowmap, float* __restrict__ Out,
        int M, int N, int ldo) {
    __shared__ unsigned short Ah_s[64 * 32], Al_s[64 * 32];
    __shared__ unsigned short Bh_s[64 * 32], Bl_s[64 * 32];
    int tid = threadIdx.x;
    int rowBase = blockIdx.y * 64, colBase = blockIdx.x * 64;
    int r = tid >> 2, e = (tid & 3) << 3;       // staging: 8 elems per thread
    int gr = rowBase + r;
    int gc = colBase + r;
    int br = (gc < N) ? (rowmap ? rowmap[gc] : gc) : -1;
    bool aok = (gr < M);
    int w = tid >> 6, lane = tid & 63, q = lane >> 4, lr = lane & 15;
    int aoff = (16 * w + lr) * 32 + q * 8;
    const uint4 z4 = {0u, 0u, 0u, 0u};
    floatx4 acc[4] = {{0.f, 0.f, 0.f, 0.f}, {0.f, 0.f, 0.f, 0.f},
                      {0.f, 0.f, 0.f, 0.f}, {0.f, 0.f, 0.f, 0.f}};
    for (int kk = 0; kk < D; kk += 32) {
        uint4 vah = aok ? *(const uint4*)(Ah + (size_t)gr * D + kk + e) : z4;
        uint4 val = aok ? *(const uint4*)(Al + (size_t)gr * D + kk + e) : z4;
        uint4 vbh = (br >= 0) ? *(const uint4*)(Bh + (size_t)br * D + kk + e) : z4;
        uint4 vbl = (br >= 0) ? *(const uint4*)(Bl + (size_t)br * D + kk + e) : z4;
        __syncthreads();
        *(uint4*)(Ah_s + r * 32 + e) = vah;
        *(uint4*)(Al_s + r * 32 + e) = val;
        *(uint4*)(Bh_s + r * 32 + e) = vbh;
        *(uint4*)(Bl_s + r * 32 + e) = vbl;
        __syncthreads();
        bf16x8 ah = *(const bf16x8*)(Ah_s + aoff);
        bf16x8 al = *(const bf16x8*)(Al_s + aoff);
#pragma unroll
        for (int tt = 0; tt < 4; ++tt) {
            int boff = (16 * tt + lr) * 32 + q * 8;
            bf16x8 bh = *(const bf16x8*)(Bh_s + boff);
            bf16x8 bl = *(const bf16x8*)(Bl_s + boff);
            acc[tt] = __builtin_amdgcn_mfma_f32_16x16x32_bf16(ah, bh, acc[tt], 0, 0, 0);
            acc[tt] = __builtin_amdgcn_mfma_f32_16x16x32_bf16(ah, bl, acc[tt], 0, 0, 0);
            acc[tt] = __builtin_amdgcn_mfma_f32_16x16x32_bf16(al, bh, acc[tt], 0, 0, 0);
        }
    }
    // C/D layout: col = lane&15, row = (lane>>4)*4 + reg
#pragma unroll
    for (int tt = 0; tt < 4; ++tt) {
        int gc2 = colBase + 16 * tt + lr;
#pragma unroll
        for (int rg = 0; rg < 4; ++rg) {
            int gr2 = rowBase + 16 * w + q * 4 + rg;
            if (gr2 < M && gc2 < N) Out[(size_t)gr2 * ldo + gc2] = acc[tt][rg];
        }
    }
}

// ---------------- row norms (one wave per row, Q rows) -------------------
__global__ void k_rownorm(const float* __restrict__ A, int ld, float* __restrict__ out) {
    int gw = (blockIdx.x * 256 + threadIdx.x) >> 6;
    int lane = threadIdx.x & 63;
    const float* row = A + (size_t)gw * ld;
    float s = 0.f;
    for (int d = lane; d < D; d += 64) { float v = row[d]; s += v * v; }
#pragma unroll
    for (int off = 32; off; off >>= 1) s += __shfl_xor(s, off);
    if (lane == 0) out[gw] = s;
}

// ---------------- per-class: Gram, K = J^{-1}+Gram, Kinv, h, btil, b0 ----
__global__ void k_class(const float* __restrict__ Yt, const int* __restrict__ rowmap,
                        const float* __restrict__ mu, const float* __restrict__ sc,
                        float* __restrict__ h, float* __restrict__ btil,
                        float* __restrict__ b0, float* __restrict__ kinv) {
    __shared__ float sv[R18][D + 4];
    __shared__ float aug[R18][40];
    __shared__ float red[256];
    __shared__ int piv;
    __shared__ float pv;
    int c = blockIdx.x, tid = threadIdx.x;
    for (int i = tid; i < R18 * D; i += 256) {
        int r = i / D, d = i - r * D;
        int rm = rowmap[c * R18 + r];
        sv[r][d] = (rm >= 0) ? Yt[(size_t)rm * NEXT + d] : 0.f;
    }
    __syncthreads();
    int wv = tid >> 6, lane = tid & 63;
    for (int p = wv; p < 171; p += 4) {
        int i = 0, rem = p;
        while (rem >= R18 - i) { rem -= R18 - i; ++i; }
        int j = i + rem;
        float s = 0.f;
        for (int d = lane; d < D; d += 64) s += sv[i][d] * sv[j][d];
#pragma unroll
        for (int off = 32; off; off >>= 1) s += __shfl_xor(s, off);
        if (lane == 0) { aug[i][j] = s; aug[j][i] = s; }
    }
    __syncthreads();
    if (tid < R18) h[c * R18 + tid] = aug[tid][R18 - 1];
    if (tid == 0) btil[c] = aug[R18 - 1][R18 - 1];
    float s0 = 0.f;
    for (int d = tid; d < D; d += 256) { float v = mu[(size_t)c * D + d]; s0 += v * v; }
    red[tid] = s0;
    __syncthreads();
    for (int st = 128; st; st >>= 1) { if (tid < st) red[tid] += red[tid + st]; __syncthreads(); }
    if (tid == 0) {
        b0[c] = red[0];
        aug[0][0] += 1.0f / sc[0];
        for (int t = 1; t <= KMAX; ++t) aug[t][t] += 1.0f;
        aug[R18 - 1][R18 - 1] += sc[192 + c];
    }
    for (int i = tid; i < R18 * R18; i += 256)
        aug[i / R18][R18 + i % R18] = (i / R18 == i % R18) ? 1.f : 0.f;
    __syncthreads();
    for (int p = 0; p < R18; ++p) {
        if (tid == 0) {
            int bi = p; float bv = fabsf(aug[p][p]);
            for (int r2 = p + 1; r2 < R18; ++r2) {
                float v = fabsf(aug[r2][p]);
                if (v > bv) { bv = v; bi = r2; }
            }
            piv = bi;
        }
        __syncthreads();
        if (piv != p && tid < 2 * R18) {
            float t = aug[p][tid]; aug[p][tid] = aug[piv][tid]; aug[piv][tid] = t;
        }
        __syncthreads();
        if (tid == 0) pv = aug[p][p];
        __syncthreads();
        if (tid < 2 * R18) aug[p][tid] /= pv;
        __syncthreads();
        if (tid < R18) red[tid] = aug[tid][p];
        __syncthreads();
        for (int i = tid; i < R18 * 2 * R18; i += 256) {
            int r2 = i / (2 * R18), col = i % (2 * R18);
            if (r2 != p) aug[r2][col] -= red[r2] * aug[p][col];
        }
        __syncthreads();
    }
    for (int i = tid; i < R18 * R18; i += 256)
        kinv[(size_t)c * R18 * R18 + i] = aug[i / R18][R18 + i % R18];
}

// ---------------- epilogue ----------------------------------------------
__global__ void k_epi(const float* __restrict__ G, const float* __restrict__ Yt,
                      const float* __restrict__ at, const float* __restrict__ a0,
                      const float* __restrict__ h, const float* __restrict__ btil,
                      const float* __restrict__ b0, const float* __restrict__ kinv,
                      const float* __restrict__ sc, float* __restrict__ out) {
    __shared__ float lk[R18 * R18], lh[R18];
    __shared__ float ldn, lbt, lb0;
    int c = blockIdx.x, tid = threadIdx.x;
    for (int i = tid; i < R18 * R18; i += 256) lk[i] = kinv[(size_t)c * R18 * R18 + i];
    if (tid < R18) lh[tid] = h[c * R18 + tid];
    if (tid == 0) { ldn = sc[128 + c]; lbt = btil[c]; lb0 = b0[c]; }
    __syncthreads();
    int q = blockIdx.y * 256 + tid;
    const float* Gr = G + (size_t)q * VROWS + c * R18;
    float g[R18];
#pragma unroll
    for (int j = 0; j < R18; ++j) g[j] = Gr[j];
    float ipt = g[R18 - 1];
#pragma unroll
    for (int j = 0; j < R18; ++j) g[j] -= lh[j];
    float corr = 0.f;
#pragma unroll
    for (int i = 0; i < R18; ++i) {
        float s = 0.f;
#pragma unroll
        for (int j = 0; j < R18; ++j) s += lk[i * R18 + j] * g[j];
        corr += g[i] * s;
    }
    float ip0 = Yt[(size_t)q * NEXT + D + c];
    float tt = at[q] - 2.f * ipt + lbt;
    float t0 = a0[q] - 2.f * ip0 + lb0;
    out[(size_t)q * C + c] = -(0.7f * ldn * (tt - corr) + 0.3f * t0);
}

extern "C" void kernel_launch(void* const* d_in, const int* in_sizes, int n_in,
                              void* d_out, int out_size, void* d_ws, size_t ws_size,
                              hipStream_t stream) {
    const float* X     = (const float*)d_in[0];
    const int*   y     = (const int*)d_in[1];
    const float* Xq    = (const float*)d_in[2];
    const float* m     = (const float*)d_in[3];
    const float* kappa = (const float*)d_in[4];
    const float* nu    = (const float*)d_in[5];
    const float* tdiag = (const float*)d_in[6];
    const float* tlow  = (const float*)d_in[7];
    float* out = (float*)d_out;

    char* w = (char*)d_ws;
    auto alloc = [&](size_t bytes) {
        char* p = w;
        w += (bytes + 255) & ~(size_t)255;
        return p;
    };
    int*   cnt    = (int*)alloc(C * 4);
    int*   idx    = (int*)alloc(C * KMAX * 4);
    int*   rowmap = (int*)alloc(VROWS * 4);
    float* sc     = (float*)alloc(256 * 4);
    float* rd     = (float*)alloc(D * 4);
    float* mu     = (float*)alloc((size_t)C * D * 4);
    float* at     = (float*)alloc(Q * 4);
    float* a0     = (float*)alloc(Q * 4);
    float* h      = (float*)alloc(C * R18 * 4);
    float* btil   = (float*)alloc(C * 4);
    float* b0     = (float*)alloc(C * 4);
    float* kinv   = (float*)alloc((size_t)C * R18 * R18 * 4);
    float* Ytout  = (float*)alloc((size_t)YPAD * NEXT * 4);          // 9.0 MB
    unsigned short* Th = (unsigned short*)alloc((size_t)YPAD * D * 2); // 4.1 MB
    unsigned short* Tl = (unsigned short*)alloc((size_t)YPAD * D * 2);
    unsigned short* Bh = (unsigned short*)alloc((size_t)NEXT * D * 2); // 0.9 MB
    unsigned short* Bl = (unsigned short*)alloc((size_t)NEXT * D * 2);
    // region reused by G (all dead before the G GEMM writes):
    char* wmark = w;
    float* Linv = (float*)alloc((size_t)D * D * 4);                  // 1.6 MB
    float* Lhat = (float*)alloc((size_t)D * D * 4);                  // 1.6 MB
    unsigned short* Ah = (unsigned short*)alloc((size_t)YPAD * D * 2); // 4.1 MB
    unsigned short* Al = (unsigned short*)alloc((size_t)YPAD * D * 2);
    w = wmark;
    float* G    = (float*)alloc((size_t)Q * VROWS * 4);              // 9.4 MB

    k_setup<<<1, 256, 0, stream>>>(y, kappa, nu, tdiag, cnt, idx, sc, rd, rowmap);
    k_mu<<<dim3(C, D / 128), 128, 0, stream>>>(X, m, cnt, idx, sc, mu);
    k_dinv<<<160, 256, 0, stream>>>(tlow, rd, Linv);
    k_lhat<<<dim3(64, 10), 256, 0, stream>>>(tlow, Linv, Lhat);
    for (int g = 1; g <= 4; ++g)
        k_linv_step<<<dim3(5 - g, 4), 256, 0, stream>>>(Lhat, Linv, g);
    k_pack_src<<<(YPAD * 160 + 255) / 256, 256, 0, stream>>>(Xq, X, m, mu, Ah, Al);
    k_pack_b<<<(NEXT * 160 + 255) / 256, 256, 0, stream>>>(Linv, mu, Bh, Bl);
    k_rownorm<<<Q / 4, 256, 0, stream>>>(Xq, D, a0);
    // Ytout[r][0:640] = tilde rows; [640:704] = x_r . mu_c
    k_mfma_nt<<<dim3(NEXT / 64, YPAD / 64), 256, 0, stream>>>(
        Ah, Al, Bh, Bl, nullptr, Ytout, YPAD, NEXT, NEXT);
    k_rownorm<<<Q / 4, 256, 0, stream>>>(Ytout, NEXT, at);
    k_class<<<C, 256, 0, stream>>>(Ytout, rowmap, mu, sc, h, btil, b0, kinv);
    k_pack_t<<<(YPAD * 160 + 255) / 256, 256, 0, stream>>>(Ytout, Th, Tl);
    // G[q][c*18+j] = x~q . v~_{c,j}
    k_mfma_nt<<<dim3(VROWS / 64, Q / 64), 256, 0, stream>>>(
        Th, Tl, Th, Tl, rowmap, G, Q, VROWS, VROWS);
    k_epi<<<dim3(C, Q / 256), 256, 0, stream>>>(G, Ytout, at, a0, h, btil, b0, kinv, sc, out);
}

// Round 5
// 347.698 us; speedup vs baseline: 2.2036x; 1.4144x over previous
//
#include <hip/hip_runtime.h>
#include <hip/hip_bf16.h>

// MetaQDA MAP. D=640, C=64, N=1024, Q=2048, REG=0.3.
// sigma_c*denom = L L^T + U_c J_c U_c^T (rank 18) => Woodbury.
// Round 5: the 4-launch k_linv_step chain (220us of launch/drain latency for
// 42 MFLOP) is fused into ONE kernel k_linv_fill: 32 WGs, each owning a
// 16-col strip and walking the block recurrence in LDS.

#define D 640
#define C 64
#define NSUP 1024
#define Q 2048
#define KMAX 16
#define R18 18           // Woodbury rank: 1 (m) + 16 (x) + 1 (mu)
#define VROWS (C * R18)  // 1152
#define YROWS 3137       // 2048 Xq + 1024 X + 1 m + 64 mu
#define YPAD 3200
#define NEXT 704         // 640 tilde cols + 64 ip0 cols

typedef __attribute__((ext_vector_type(8))) short bf16x8;
typedef __attribute__((ext_vector_type(4))) float floatx4;

__device__ __forceinline__ unsigned short f2bf(float x) {
    unsigned int u = __float_as_uint(x);
    unsigned int r = u + 0x7FFFu + ((u >> 16) & 1u);
    return (unsigned short)(r >> 16);
}

// ---------------- setup: class lists, scalars, rowmap --------------------
__global__ void k_setup(const int* __restrict__ y, const float* __restrict__ kappa,
                        const float* __restrict__ nu, const float* __restrict__ diag,
                        int* __restrict__ cnt, int* __restrict__ idx,
                        float* __restrict__ sc, float* __restrict__ rd,
                        int* __restrict__ rowmap) {
    __shared__ int lc[C];
    int tid = threadIdx.x;
    if (tid < C) lc[tid] = 0;
    __syncthreads();
    for (int n = tid; n < NSUP; n += 256) {
        int c = y[n];
        int k = atomicAdd(&lc[c], 1);
        if (k < KMAX) idx[c * KMAX + k] = n;
    }
    __syncthreads();
    for (int d = tid; d < D; d += 256) rd[d] = 1.0f / fabsf(diag[d]);
    if (tid < C) {
        int n = lc[tid]; if (n > KMAX) n = KMAX;
        cnt[tid] = n;
        float kap = fabsf(kappa[0]) + 1e-6f;
        float nuv = fmaxf(nu[0], (float)(D - 1) + 1e-6f);
        float Ncf = (float)n;
        sc[64 + tid]  = Ncf / (kap + Ncf);            // w_c
        sc[128 + tid] = nuv + Ncf + (float)(D + 2);   // denom_c
        sc[192 + tid] = -1.0f / (kap + Ncf);          // J^{-1} last diag
        if (tid == 0) { sc[0] = kap; sc[1] = nuv; }
    }
    __syncthreads();
    for (int i = tid; i < VROWS; i += 256) {
        int c = i / R18, j = i - c * R18;
        int nc = lc[c] < KMAX ? lc[c] : KMAX;
        int rm;
        if (j == 0) rm = Q + NSUP;                       // m~
        else if (j <= KMAX) rm = (j - 1 < nc) ? Q + idx[c * KMAX + j - 1] : -1;
        else rm = Q + NSUP + 1 + c;                      // mu~
        rowmap[i] = rm;
    }
}

// ---------------- mu[c][d] = (1-w)*m + w*mean_c --------------------------
__global__ void k_mu(const float* __restrict__ X, const float* __restrict__ m,
                     const int* __restrict__ cnt, const int* __restrict__ idx,
                     const float* __restrict__ sc, float* __restrict__ mu) {
    int c = blockIdx.x;
    int d = blockIdx.y * 128 + threadIdx.x;
    int n = cnt[c];
    float s = 0.f;
    for (int k = 0; k < n; ++k) s += X[(size_t)idx[c * KMAX + k] * D + d];
    float w = sc[64 + c];
    float mean = (n > 0) ? s / (float)n : 0.f;
    mu[(size_t)c * D + d] = (1.f - w) * m[d] + w * mean;
}

// ---------------- Dinv: invert 5 diagonal 128x128 blocks into Linv -------
__global__ void k_dinv(const float* __restrict__ tlow, const float* __restrict__ rd,
                       float* __restrict__ Linv) {
    __shared__ float Lst[128 * 128];
    int tid = threadIdx.x;
    int b = blockIdx.x >> 5;
    int j = ((blockIdx.x & 31) << 2) + (tid >> 6);
    int lane = tid & 63;
    int bB = b * 128;
    for (int e = tid; e < 128 * 128; e += 256) {
        int c = e & 127, r = e >> 7;
        float v;
        if (r == c) v = 1.0f;
        else if (r > c) v = rd[bB + r] * tlow[(size_t)(bB + r) * D + bB + c];
        else v = 0.f;
        Lst[c * 128 + (r ^ (c & 63))] = v;
    }
    __syncthreads();
    float rd0 = rd[bB + lane], rd1 = rd[bB + 64 + lane];
    float acc0 = 0.f, acc1 = 0.f, zz0 = 0.f, zz1 = 0.f;
    for (int i = j; i < 128; ++i) {
        int ri = i >> 6, il = i & 63;
        float av = (ri == 0) ? acc0 : acc1;
        float ai = __shfl(av, il);
        float zi = (i == j) ? __shfl((ri == 0) ? rd0 : rd1, il) : -ai;
        int sw = i & 63;
        float l0 = Lst[i * 128 + (lane ^ sw)];
        float l1 = Lst[i * 128 + 64 + (lane ^ sw)];
        if (lane > i) acc0 += l0 * zi;
        if (64 + lane > i) acc1 += l1 * zi;
        if (lane == i) zz0 = zi;
        if (64 + lane == i) zz1 = zi;
    }
    Linv[(size_t)(bB + lane) * D + bB + j] = zz0;
    Linv[(size_t)(bB + 64 + lane) * D + bB + j] = zz1;
}

// ---------------- Lhat_ik = Dinv_i * L_ik (strict-lower blocks) ----------
__global__ void k_lhat(const float* __restrict__ tlow, const float* __restrict__ Linv,
                       float* __restrict__ Lhat) {
    const int bi_tab[10] = {1, 2, 2, 3, 3, 3, 4, 4, 4, 4};
    const int bk_tab[10] = {0, 0, 1, 0, 1, 2, 0, 1, 2, 3};
    int p = blockIdx.y;
    int bi = bi_tab[p], bk = bk_tab[p];
    int tid = threadIdx.x;
    int c = tid & 127;
    int r = (blockIdx.x << 1) + (tid >> 7);
    const float* drow = Linv + (size_t)(bi * 128 + r) * D + bi * 128;
    const float* lcol = tlow + (size_t)(bi * 128) * D + bk * 128 + c;
    float s = 0.f;
#pragma unroll 4
    for (int t = 0; t < 128; ++t) s += drow[t] * lcol[(size_t)t * D];
    Lhat[(size_t)(bi * 128 + r) * D + bk * 128 + c] = s;
}

// ---------------- Linv off-diag: fused strip recurrence ------------------
// 32 WGs: (b = blockIdx.x>>3) x (strip = blockIdx.x&7, 16 cols).
// S_b = Dinv_b[:,strip]; for i>b: S_i = -sum_{j=b..i-1} Lhat_ij * S_j.
__global__ __launch_bounds__(256) void k_linv_fill(const float* __restrict__ Lhat,
                                                   float* __restrict__ Linv) {
    __shared__ __align__(16) float S[4][128][20];   // 40 KB
    __shared__ __align__(16) float LhT[32][132];    // 17 KB (transposed chunk)
    int tid = threadIdx.x;
    int b = blockIdx.x >> 3, strip = blockIdx.x & 7;
    int bB = b * 128, cB = bB + strip * 16;
    int ty = tid >> 2, tx = tid & 3;                // rows {2ty,2ty+1}, cols 4tx..
    {   // load S_b strip from the Dinv block already in Linv
        int r = tid >> 1, c0 = (tid & 1) * 8;
        const float* src = Linv + (size_t)(bB + r) * D + cB + c0;
#pragma unroll
        for (int e = 0; e < 8; ++e) S[0][r][c0 + e] = src[e];
    }
    __syncthreads();
    for (int i = b + 1; i <= 4; ++i) {
        float acc[2][4] = {};
        for (int j = b; j < i; ++j) {
            for (int k0 = 0; k0 < 128; k0 += 32) {
                __syncthreads();                    // LhT reuse guard
                {
                    int r = tid >> 1, kk = (tid & 1) * 16;
                    const float* src = Lhat + (size_t)(i * 128 + r) * D + j * 128 + k0 + kk;
#pragma unroll
                    for (int e = 0; e < 16; ++e) LhT[kk + e][r] = src[e];
                }
                __syncthreads();
#pragma unroll 4
                for (int k = 0; k < 32; ++k) {
                    float a0 = LhT[k][ty * 2], a1 = LhT[k][ty * 2 + 1];
                    float4 bv = *(const float4*)&S[j - b][k0 + k][tx * 4];
                    acc[0][0] += a0 * bv.x; acc[0][1] += a0 * bv.y;
                    acc[0][2] += a0 * bv.z; acc[0][3] += a0 * bv.w;
                    acc[1][0] += a1 * bv.x; acc[1][1] += a1 * bv.y;
                    acc[1][2] += a1 * bv.z; acc[1][3] += a1 * bv.w;
                }
            }
        }
        int si = i - b;
#pragma unroll
        for (int rr = 0; rr < 2; ++rr) {
            int r = ty * 2 + rr;
#pragma unroll
            for (int cc = 0; cc < 4; ++cc) {
                float v = -acc[rr][cc];
                if (si <= 3) S[si][r][tx * 4 + cc] = v;
                Linv[(size_t)(i * 128 + r) * D + cB + tx * 4 + cc] = v;
            }
        }
        // next stage's two barriers (LhT guard + staging) order these S writes
    }
}

// ---------------- pack A-side: [Xq; X; m; mu] -> hi/lo bf16 [3200x640] ---
__global__ void k_pack_src(const float* __restrict__ Xq, const float* __restrict__ X,
                           const float* __restrict__ m, const float* __restrict__ mu,
                           unsigned short* __restrict__ hi, unsigned short* __restrict__ lo) {
    int gid = blockIdx.x * 256 + threadIdx.x;       // one per 4 elems
    int row = gid / 160, c = (gid - row * 160) * 4;
    if (row >= YPAD) return;
    float4 v = {0.f, 0.f, 0.f, 0.f};
    if (row < Q) v = *(const float4*)(Xq + (size_t)row * D + c);
    else if (row < Q + NSUP) v = *(const float4*)(X + (size_t)(row - Q) * D + c);
    else if (row == Q + NSUP) v = *(const float4*)(m + c);
    else if (row < YROWS) v = *(const float4*)(mu + (size_t)(row - (Q + NSUP + 1)) * D + c);
    float vv[4] = {v.x, v.y, v.z, v.w};
    ushort4 h, l;
    unsigned short* hp = (unsigned short*)&h;
    unsigned short* lp = (unsigned short*)&l;
#pragma unroll
    for (int i = 0; i < 4; ++i) {
        unsigned short hb = f2bf(vv[i]);
        float hf = __uint_as_float((unsigned int)hb << 16);
        hp[i] = hb;
        lp[i] = f2bf(vv[i] - hf);
    }
    *(ushort4*)(hi + (size_t)row * D + c) = h;
    *(ushort4*)(lo + (size_t)row * D + c) = l;
}

// ---------------- pack B-side: [Linv (upper masked); mu] -> [704x640] ----
__global__ void k_pack_b(const float* __restrict__ Linv, const float* __restrict__ mu,
                         unsigned short* __restrict__ hi, unsigned short* __restrict__ lo) {
    int gid = blockIdx.x * 256 + threadIdx.x;
    int row = gid / 160, c = (gid - row * 160) * 4;
    if (row >= NEXT) return;
    float4 v;
    if (row < D) v = *(const float4*)(Linv + (size_t)row * D + c);
    else v = *(const float4*)(mu + (size_t)(row - D) * D + c);
    float vv[4] = {v.x, v.y, v.z, v.w};
    ushort4 h, l;
    unsigned short* hp = (unsigned short*)&h;
    unsigned short* lp = (unsigned short*)&l;
#pragma unroll
    for (int i = 0; i < 4; ++i) {
        float x = (row < D && c + i > row) ? 0.f : vv[i];   // strict upper = 0
        unsigned short hb = f2bf(x);
        float hf = __uint_as_float((unsigned int)hb << 16);
        hp[i] = hb;
        lp[i] = f2bf(x - hf);
    }
    *(ushort4*)(hi + (size_t)row * D + c) = h;
    *(ushort4*)(lo + (size_t)row * D + c) = l;
}

// ---------------- pack Yt (f32, ld=704, cols 0..639) -> hi/lo ------------
__global__ void k_pack_t(const float* __restrict__ Yt,
                         unsigned short* __restrict__ hi, unsigned short* __restrict__ lo) {
    int gid = blockIdx.x * 256 + threadIdx.x;
    int row = gid / 160, c = (gid - row * 160) * 4;
    if (row >= YPAD) return;
    float4 v = *(const float4*)(Yt + (size_t)row * NEXT + c);
    float vv[4] = {v.x, v.y, v.z, v.w};
    ushort4 h, l;
    unsigned short* hp = (unsigned short*)&h;
    unsigned short* lp = (unsigned short*)&l;
#pragma unroll
    for (int i = 0; i < 4; ++i) {
        unsigned short hb = f2bf(vv[i]);
        float hf = __uint_as_float((unsigned int)hb << 16);
        hp[i] = hb;
        lp[i] = f2bf(vv[i] - hf);
    }
    *(ushort4*)(hi + (size_t)row * D + c) = h;
    *(ushort4*)(lo + (size_t)row * D + c) = l;
}

// ---------------- split-bf16 MFMA NT GEMM, 64x64 tile --------------------
__global__ __launch_bounds__(256) void k_mfma_nt(
        const unsigned short* __restrict__ Ah, const unsigned short* __restrict__ Al,
        const unsigned short* __restrict__ Bh, const unsigned short* __restrict__ Bl,
        const int* __restrict__ rowmap, float* __restrict__ Out,
        int M, int N, int ldo) {
    __shared__ unsigned short Ah_s[64 * 32], Al_s[64 * 32];
    __shared__ unsigned short Bh_s[64 * 32], Bl_s[64 * 32];
    int tid = threadIdx.x;
    int rowBase = blockIdx.y * 64, colBase = blockIdx.x * 64;
    int r = tid >> 2, e = (tid & 3) << 3;
    int gr = rowBase + r;
    int gc = colBase + r;
    int br = (gc < N) ? (rowmap ? rowmap[gc] : gc) : -1;
    bool aok = (gr < M);
    int w = tid >> 6, lane = tid & 63, q = lane >> 4, lr = lane & 15;
    int aoff = (16 * w + lr) * 32 + q * 8;
    const uint4 z4 = {0u, 0u, 0u, 0u};
    floatx4 acc[4] = {{0.f, 0.f, 0.f, 0.f}, {0.f, 0.f, 0.f, 0.f},
                      {0.f, 0.f, 0.f, 0.f}, {0.f, 0.f, 0.f, 0.f}};
    for (int kk = 0; kk < D; kk += 32) {
        uint4 vah = aok ? *(const uint4*)(Ah + (size_t)gr * D + kk + e) : z4;
        uint4 val = aok ? *(const uint4*)(Al + (size_t)gr * D + kk + e) : z4;
        uint4 vbh = (br >= 0) ? *(const uint4*)(Bh + (size_t)br * D + kk + e) : z4;
        uint4 vbl = (br >= 0) ? *(const uint4*)(Bl + (size_t)br * D + kk + e) : z4;
        __syncthreads();
        *(uint4*)(Ah_s + r * 32 + e) = vah;
        *(uint4*)(Al_s + r * 32 + e) = val;
        *(uint4*)(Bh_s + r * 32 + e) = vbh;
        *(uint4*)(Bl_s + r * 32 + e) = vbl;
        __syncthreads();
        bf16x8 ah = *(const bf16x8*)(Ah_s + aoff);
        bf16x8 al = *(const bf16x8*)(Al_s + aoff);
#pragma unroll
        for (int tt = 0; tt < 4; ++tt) {
            int boff = (16 * tt + lr) * 32 + q * 8;
            bf16x8 bh = *(const bf16x8*)(Bh_s + boff);
            bf16x8 bl = *(const bf16x8*)(Bl_s + boff);
            acc[tt] = __builtin_amdgcn_mfma_f32_16x16x32_bf16(ah, bh, acc[tt], 0, 0, 0);
            acc[tt] = __builtin_amdgcn_mfma_f32_16x16x32_bf16(ah, bl, acc[tt], 0, 0, 0);
            acc[tt] = __builtin_amdgcn_mfma_f32_16x16x32_bf16(al, bh, acc[tt], 0, 0, 0);
        }
    }
#pragma unroll
    for (int tt = 0; tt < 4; ++tt) {
        int gc2 = colBase + 16 * tt + lr;
#pragma unroll
        for (int rg = 0; rg < 4; ++rg) {
            int gr2 = rowBase + 16 * w + q * 4 + rg;
            if (gr2 < M && gc2 < N) Out[(size_t)gr2 * ldo + gc2] = acc[tt][rg];
        }
    }
}

// ---------------- row norms (one wave per row, Q rows) -------------------
__global__ void k_rownorm(const float* __restrict__ A, int ld, float* __restrict__ out) {
    int gw = (blockIdx.x * 256 + threadIdx.x) >> 6;
    int lane = threadIdx.x & 63;
    const float* row = A + (size_t)gw * ld;
    float s = 0.f;
    for (int d = lane; d < D; d += 64) { float v = row[d]; s += v * v; }
#pragma unroll
    for (int off = 32; off; off >>= 1) s += __shfl_xor(s, off);
    if (lane == 0) out[gw] = s;
}

// ---------------- per-class: Gram, K = J^{-1}+Gram, Kinv, h, btil, b0 ----
__global__ void k_class(const float* __restrict__ Yt, const int* __restrict__ rowmap,
                        const float* __restrict__ mu, const float* __restrict__ sc,
                        float* __restrict__ h, float* __restrict__ btil,
                        float* __restrict__ b0, float* __restrict__ kinv) {
    __shared__ float sv[R18][D + 4];
    __shared__ float aug[R18][40];
    __shared__ float red[256];
    __shared__ int piv;
    __shared__ float pv;
    int c = blockIdx.x, tid = threadIdx.x;
    for (int i = tid; i < R18 * D; i += 256) {
        int r = i / D, d = i - r * D;
        int rm = rowmap[c * R18 + r];
        sv[r][d] = (rm >= 0) ? Yt[(size_t)rm * NEXT + d] : 0.f;
    }
    __syncthreads();
    int wv = tid >> 6, lane = tid & 63;
    for (int p = wv; p < 171; p += 4) {
        int i = 0, rem = p;
        while (rem >= R18 - i) { rem -= R18 - i; ++i; }
        int j = i + rem;
        float s = 0.f;
        for (int d = lane; d < D; d += 64) s += sv[i][d] * sv[j][d];
#pragma unroll
        for (int off = 32; off; off >>= 1) s += __shfl_xor(s, off);
        if (lane == 0) { aug[i][j] = s; aug[j][i] = s; }
    }
    __syncthreads();
    if (tid < R18) h[c * R18 + tid] = aug[tid][R18 - 1];
    if (tid == 0) btil[c] = aug[R18 - 1][R18 - 1];
    float s0 = 0.f;
    for (int d = tid; d < D; d += 256) { float v = mu[(size_t)c * D + d]; s0 += v * v; }
    red[tid] = s0;
    __syncthreads();
    for (int st = 128; st; st >>= 1) { if (tid < st) red[tid] += red[tid + st]; __syncthreads(); }
    if (tid == 0) {
        b0[c] = red[0];
        aug[0][0] += 1.0f / sc[0];
        for (int t = 1; t <= KMAX; ++t) aug[t][t] += 1.0f;
        aug[R18 - 1][R18 - 1] += sc[192 + c];
    }
    for (int i = tid; i < R18 * R18; i += 256)
        aug[i / R18][R18 + i % R18] = (i / R18 == i % R18) ? 1.f : 0.f;
    __syncthreads();
    for (int p = 0; p < R18; ++p) {
        if (tid == 0) {
            int bi = p; float bv = fabsf(aug[p][p]);
            for (int r2 = p + 1; r2 < R18; ++r2) {
                float v = fabsf(aug[r2][p]);
                if (v > bv) { bv = v; bi = r2; }
            }
            piv = bi;
        }
        __syncthreads();
        if (piv != p && tid < 2 * R18) {
            float t = aug[p][tid]; aug[p][tid] = aug[piv][tid]; aug[piv][tid] = t;
        }
        __syncthreads();
        if (tid == 0) pv = aug[p][p];
        __syncthreads();
        if (tid < 2 * R18) aug[p][tid] /= pv;
        __syncthreads();
        if (tid < R18) red[tid] = aug[tid][p];
        __syncthreads();
        for (int i = tid; i < R18 * 2 * R18; i += 256) {
            int r2 = i / (2 * R18), col = i % (2 * R18);
            if (r2 != p) aug[r2][col] -= red[r2] * aug[p][col];
        }
        __syncthreads();
    }
    for (int i = tid; i < R18 * R18; i += 256)
        kinv[(size_t)c * R18 * R18 + i] = aug[i / R18][R18 + i % R18];
}

// ---------------- epilogue ----------------------------------------------
__global__ void k_epi(const float* __restrict__ G, const float* __restrict__ Yt,
                      const float* __restrict__ at, const float* __restrict__ a0,
                      const float* __restrict__ h, const float* __restrict__ btil,
                      const float* __restrict__ b0, const float* __restrict__ kinv,
                      const float* __restrict__ sc, float* __restrict__ out) {
    __shared__ float lk[R18 * R18], lh[R18];
    __shared__ float ldn, lbt, lb0;
    int c = blockIdx.x, tid = threadIdx.x;
    for (int i = tid; i < R18 * R18; i += 256) lk[i] = kinv[(size_t)c * R18 * R18 + i];
    if (tid < R18) lh[tid] = h[c * R18 + tid];
    if (tid == 0) { ldn = sc[128 + c]; lbt = btil[c]; lb0 = b0[c]; }
    __syncthreads();
    int q = blockIdx.y * 256 + tid;
    const float* Gr = G + (size_t)q * VROWS + c * R18;
    float g[R18];
#pragma unroll
    for (int j = 0; j < R18; ++j) g[j] = Gr[j];
    float ipt = g[R18 - 1];
#pragma unroll
    for (int j = 0; j < R18; ++j) g[j] -= lh[j];
    float corr = 0.f;
#pragma unroll
    for (int i = 0; i < R18; ++i) {
        float s = 0.f;
#pragma unroll
        for (int j = 0; j < R18; ++j) s += lk[i * R18 + j] * g[j];
        corr += g[i] * s;
    }
    float ip0 = Yt[(size_t)q * NEXT + D + c];
    float tt = at[q] - 2.f * ipt + lbt;
    float t0 = a0[q] - 2.f * ip0 + lb0;
    out[(size_t)q * C + c] = -(0.7f * ldn * (tt - corr) + 0.3f * t0);
}

extern "C" void kernel_launch(void* const* d_in, const int* in_sizes, int n_in,
                              void* d_out, int out_size, void* d_ws, size_t ws_size,
                              hipStream_t stream) {
    const float* X     = (const float*)d_in[0];
    const int*   y     = (const int*)d_in[1];
    const float* Xq    = (const float*)d_in[2];
    const float* m     = (const float*)d_in[3];
    const float* kappa = (const float*)d_in[4];
    const float* nu    = (const float*)d_in[5];
    const float* tdiag = (const float*)d_in[6];
    const float* tlow  = (const float*)d_in[7];
    float* out = (float*)d_out;

    char* w = (char*)d_ws;
    auto alloc = [&](size_t bytes) {
        char* p = w;
        w += (bytes + 255) & ~(size_t)255;
        return p;
    };
    int*   cnt    = (int*)alloc(C * 4);
    int*   idx    = (int*)alloc(C * KMAX * 4);
    int*   rowmap = (int*)alloc(VROWS * 4);
    float* sc     = (float*)alloc(256 * 4);
    float* rd     = (float*)alloc(D * 4);
    float* mu     = (float*)alloc((size_t)C * D * 4);
    float* at     = (float*)alloc(Q * 4);
    float* a0     = (float*)alloc(Q * 4);
    float* h      = (float*)alloc(C * R18 * 4);
    float* btil   = (float*)alloc(C * 4);
    float* b0     = (float*)alloc(C * 4);
    float* kinv   = (float*)alloc((size_t)C * R18 * R18 * 4);
    float* Ytout  = (float*)alloc((size_t)YPAD * NEXT * 4);          // 9.0 MB
    unsigned short* Th = (unsigned short*)alloc((size_t)YPAD * D * 2); // 4.1 MB
    unsigned short* Tl = (unsigned short*)alloc((size_t)YPAD * D * 2);
    unsigned short* Bh = (unsigned short*)alloc((size_t)NEXT * D * 2); // 0.9 MB
    unsigned short* Bl = (unsigned short*)alloc((size_t)NEXT * D * 2);
    // region reused by G (all dead before the G GEMM writes):
    char* wmark = w;
    float* Linv = (float*)alloc((size_t)D * D * 4);                  // 1.6 MB
    float* Lhat = (float*)alloc((size_t)D * D * 4);                  // 1.6 MB
    unsigned short* Ah = (unsigned short*)alloc((size_t)YPAD * D * 2); // 4.1 MB
    unsigned short* Al = (unsigned short*)alloc((size_t)YPAD * D * 2);
    w = wmark;
    float* G    = (float*)alloc((size_t)Q * VROWS * 4);              // 9.4 MB

    k_setup<<<1, 256, 0, stream>>>(y, kappa, nu, tdiag, cnt, idx, sc, rd, rowmap);
    k_mu<<<dim3(C, D / 128), 128, 0, stream>>>(X, m, cnt, idx, sc, mu);
    k_dinv<<<160, 256, 0, stream>>>(tlow, rd, Linv);
    k_lhat<<<dim3(64, 10), 256, 0, stream>>>(tlow, Linv, Lhat);
    k_linv_fill<<<32, 256, 0, stream>>>(Lhat, Linv);
    k_pack_src<<<(YPAD * 160 + 255) / 256, 256, 0, stream>>>(Xq, X, m, mu, Ah, Al);
    k_pack_b<<<(NEXT * 160 + 255) / 256, 256, 0, stream>>>(Linv, mu, Bh, Bl);
    k_rownorm<<<Q / 4, 256, 0, stream>>>(Xq, D, a0);
    // Ytout[r][0:640] = tilde rows; [640:704] = x_r . mu_c
    k_mfma_nt<<<dim3(NEXT / 64, YPAD / 64), 256, 0, stream>>>(
        Ah, Al, Bh, Bl, nullptr, Ytout, YPAD, NEXT, NEXT);
    k_rownorm<<<Q / 4, 256, 0, stream>>>(Ytout, NEXT, at);
    k_class<<<C, 256, 0, stream>>>(Ytout, rowmap, mu, sc, h, btil, b0, kinv);
    k_pack_t<<<(YPAD * 160 + 255) / 256, 256, 0, stream>>>(Ytout, Th, Tl);
    // G[q][c*18+j] = x~q . v~_{c,j}
    k_mfma_nt<<<dim3(VROWS / 64, Q / 64), 256, 0, stream>>>(
        Th, Tl, Th, Tl, rowmap, G, Q, VROWS, VROWS);
    k_epi<<<dim3(C, Q / 256), 256, 0, stream>>>(G, Ytout, at, a0, h, btil, b0, kinv, sc, out);
}